// Round 16
// baseline (294.229 us; speedup 1.0000x reference)
//
#include <hip/hip_runtime.h>
#include <hip/hip_bf16.h>
#include <hip/hip_fp16.h>

#define DD 128
#define BN_EPS 1e-5f
#define SPMM_BLOCKS 3125     // ngroups=6250 -> exactly 2 groups/block
#define SCAT_BLOCKS 1264     // 158 slices x 8 partitions; 782+1264=2046 <= 2048 co-resident
#define NSLOT 64             // stat partial slots
#define CAP 32
#define OVF_MAX 8192

typedef __attribute__((ext_vector_type(8))) short bf16x8;
typedef __attribute__((ext_vector_type(4))) float f32x4;

static __device__ __forceinline__ unsigned short f2bf(float f) {
    __hip_bfloat16 h = __float2bfloat16(f);   // RNE
    return *reinterpret_cast<unsigned short*>(&h);
}
static __device__ __forceinline__ float bf2f(unsigned short u) {
    return __uint_as_float(((unsigned)u) << 16);
}
static __device__ __forceinline__ unsigned pack_rec(int col, float val) {
    __half h = __float2half(val);
    unsigned hb = *reinterpret_cast<unsigned short*>(&h);
    return (unsigned)col | (hb << 16);
}
static __device__ __forceinline__ float rec_val(unsigned rec) {
    unsigned short hb = (unsigned short)(rec >> 16);
    __half h = *reinterpret_cast<__half*>(&hb);
    return __half2float(h);
}

// ---------------------------------------------------------------- prep + zero
__global__ __launch_bounds__(256) void prep_zero_k(
    const float* __restrict__ W, const float* __restrict__ Wself,
    unsigned short* __restrict__ Wt4, int* __restrict__ zp, int nz)
{
    if (blockIdx.x < 32) {
        int mat   = blockIdx.x >> 3;
        int chunk = blockIdx.x & 7;
        int layer = mat >> 1;
        const float* src = (mat & 1) ? (Wself + layer * 16384) : (W + layer * 16384);
        unsigned short* dst = Wt4 + (size_t)mat * 16384;
        int base = chunk * 2048 + threadIdx.x * 4;
        #pragma unroll
        for (int rep = 0; rep < 2; rep++) {
            int i = base + rep * 1024;          // i = k*128 + n
            float4 v = *(const float4*)&src[i];
            int k = i >> 7, n = i & 127;
            dst[(n + 0) * 128 + k] = f2bf(v.x);
            dst[(n + 1) * 128 + k] = f2bf(v.y);
            dst[(n + 2) * 128 + k] = f2bf(v.z);
            dst[(n + 3) * 128 + k] = f2bf(v.w);
        }
    } else {
        int i = (blockIdx.x - 32) * 256 + threadIdx.x;
        if (i < nz) zp[i] = 0;
    }
}

// ---------------------------------------------------------------- scatter body
static __device__ __forceinline__ void scatter_body(
    int j, int nsl, int p,
    const int* __restrict__ arow, const int* __restrict__ acol,
    const float* __restrict__ aval, int* __restrict__ cnt,
    unsigned* __restrict__ bucket, int* __restrict__ ovfc,
    int2* __restrict__ ovf, int E, int rpp)
{
    const int slice = j >> 3;
    const int e0 = (int)((long long)E * slice / nsl);
    const int e1 = (int)((long long)E * (slice + 1) / nsl);
    for (int e = e0 + threadIdx.x; e < e1; e += 256) {
        int r = arow[e];
        if (r / rpp == p) {
            int pos = atomicAdd(&cnt[r], 1);
            unsigned rec = pack_rec(acol[e], aval[e]);
            if (pos < CAP) {
                bucket[(size_t)r * CAP + pos] = rec;
            } else {
                int oi = atomicAdd(ovfc, 1);
                if (oi < OVF_MAX) ovf[oi] = make_int2(r, (int)rec);
            }
        }
    }
}

// ---------------------------------------------------------------- gemm L0 + scatter
// blocks [0, gemm_grid): gemm; blocks [gemm_grid, ..): scatter
__global__ __launch_bounds__(256) void gemm_l0_scatter(
    const float* __restrict__ A,
    const unsigned short* __restrict__ Wt, const unsigned short* __restrict__ Wst,
    const float* __restrict__ bias,
    unsigned short* __restrict__ support, float* __restrict__ outb, int N, int gemm_grid,
    const int* __restrict__ arow, const int* __restrict__ acol,
    const float* __restrict__ aval, int* __restrict__ cnt,
    unsigned* __restrict__ bucket, int* __restrict__ ovfc,
    int2* __restrict__ ovf, int E, int rpp)
{
    if (blockIdx.x >= gemm_grid) {
        int j = blockIdx.x - gemm_grid;
        int nsl = (gridDim.x - gemm_grid) >> 3;
        int p = blockIdx.x & 7;           // XCD-aligned partition (whole grid co-resident)
        scatter_body(j, nsl, p, arow, acol, aval, cnt, bucket, ovfc, ovf, E, rpp);
        return;
    }

    const int wave = threadIdx.x >> 6;
    const int lane = threadIdx.x & 63;
    const int m    = lane & 15;
    const int quad = lane >> 4;
    const int row0 = blockIdx.x * 64 + wave * 16;

    int ar = row0 + m; if (ar > N - 1) ar = N - 1;
    const float* Ar = A + (size_t)ar * 128;
    bf16x8 af[4];
    #pragma unroll
    for (int ch = 0; ch < 4; ch++) {
        int k0 = ch * 32 + quad * 8;
        float4 u = *(const float4*)&Ar[k0];
        float4 v = *(const float4*)&Ar[k0 + 4];
        float vals[8] = {u.x, u.y, u.z, u.w, v.x, v.y, v.z, v.w};
        #pragma unroll
        for (int jj = 0; jj < 8; jj++) af[ch][jj] = (short)f2bf(vals[jj]);
    }

    f32x4 acc1[8], acc2[8];
    #pragma unroll
    for (int nt = 0; nt < 8; nt++) { acc1[nt] = (f32x4)(0.f); acc2[nt] = (f32x4)(0.f); }

    #pragma unroll
    for (int nt = 0; nt < 8; nt++) {
        const bf16x8* B1 = (const bf16x8*)(Wt  + ((size_t)(nt * 16 + m)) * 128 + quad * 8);
        const bf16x8* B2 = (const bf16x8*)(Wst + ((size_t)(nt * 16 + m)) * 128 + quad * 8);
        acc1[nt] = __builtin_amdgcn_mfma_f32_16x16x32_bf16(af[0], B1[0],  acc1[nt], 0, 0, 0);
        acc2[nt] = __builtin_amdgcn_mfma_f32_16x16x32_bf16(af[0], B2[0],  acc2[nt], 0, 0, 0);
        acc1[nt] = __builtin_amdgcn_mfma_f32_16x16x32_bf16(af[1], B1[4],  acc1[nt], 0, 0, 0);
        acc2[nt] = __builtin_amdgcn_mfma_f32_16x16x32_bf16(af[1], B2[4],  acc2[nt], 0, 0, 0);
        acc1[nt] = __builtin_amdgcn_mfma_f32_16x16x32_bf16(af[2], B1[8],  acc1[nt], 0, 0, 0);
        acc2[nt] = __builtin_amdgcn_mfma_f32_16x16x32_bf16(af[2], B2[8],  acc2[nt], 0, 0, 0);
        acc1[nt] = __builtin_amdgcn_mfma_f32_16x16x32_bf16(af[3], B1[12], acc1[nt], 0, 0, 0);
        acc2[nt] = __builtin_amdgcn_mfma_f32_16x16x32_bf16(af[3], B2[12], acc2[nt], 0, 0, 0);
    }

    float bv[8];
    #pragma unroll
    for (int nt = 0; nt < 8; nt++) bv[nt] = bias[nt * 16 + m];

    // C/D layout: col = lane&15, row = quad*4 + reg
    #pragma unroll
    for (int r = 0; r < 4; r++) {
        int orow = row0 + quad * 4 + r;
        if (orow < N) {
            size_t base = (size_t)orow * 128 + m;
            #pragma unroll
            for (int nt = 0; nt < 8; nt++) {
                support[base + nt * 16] = f2bf(acc1[nt][r]);
                outb[base + nt * 16]    = acc2[nt][r] + bv[nt];
            }
        }
    }
}

// ---------------------------------------------------------------- gemm L1 + BN prologue
__global__ __launch_bounds__(256) void gemm_bn_k(
    const float* __restrict__ A,
    const unsigned short* __restrict__ Wt, const unsigned short* __restrict__ Wst,
    const float* __restrict__ bias,
    const float* __restrict__ partials, const float* __restrict__ gamma,
    const float* __restrict__ beta, float invN,
    unsigned short* __restrict__ support, float* __restrict__ outb, int N)
{
    __shared__ float tot[256];
    __shared__ float ssc[128], ssh[128];
    {
        float a = 0.f;
        #pragma unroll 8
        for (int s = 0; s < NSLOT; s++)
            a += partials[(size_t)s * 256 + threadIdx.x];
        tot[threadIdx.x] = a;
    }
    __syncthreads();
    if (threadIdx.x < 128) {
        int c = threadIdx.x;
        float mean = tot[c] * invN;
        float var  = tot[128 + c] * invN - mean * mean;
        float sc   = gamma[c] * rsqrtf(var + BN_EPS);
        ssc[c] = sc;
        ssh[c] = beta[c] - mean * sc;
    }
    __syncthreads();

    const int wave = threadIdx.x >> 6;
    const int lane = threadIdx.x & 63;
    const int m    = lane & 15;
    const int quad = lane >> 4;
    const int row0 = blockIdx.x * 64 + wave * 16;

    int ar = row0 + m; if (ar > N - 1) ar = N - 1;
    const float* Ar = A + (size_t)ar * 128;
    bf16x8 af[4];
    #pragma unroll
    for (int ch = 0; ch < 4; ch++) {
        int k0 = ch * 32 + quad * 8;
        float4 u = *(const float4*)&Ar[k0];
        float4 v = *(const float4*)&Ar[k0 + 4];
        float vals[8] = {u.x, u.y, u.z, u.w, v.x, v.y, v.z, v.w};
        #pragma unroll
        for (int j = 0; j < 8; j++) {
            float val = vals[j] * ssc[k0 + j] + ssh[k0 + j];
            val = val > 0.f ? val : 0.f;
            af[ch][j] = (short)f2bf(val);
        }
    }

    f32x4 acc1[8], acc2[8];
    #pragma unroll
    for (int nt = 0; nt < 8; nt++) { acc1[nt] = (f32x4)(0.f); acc2[nt] = (f32x4)(0.f); }

    #pragma unroll
    for (int nt = 0; nt < 8; nt++) {
        const bf16x8* B1 = (const bf16x8*)(Wt  + ((size_t)(nt * 16 + m)) * 128 + quad * 8);
        const bf16x8* B2 = (const bf16x8*)(Wst + ((size_t)(nt * 16 + m)) * 128 + quad * 8);
        acc1[nt] = __builtin_amdgcn_mfma_f32_16x16x32_bf16(af[0], B1[0],  acc1[nt], 0, 0, 0);
        acc2[nt] = __builtin_amdgcn_mfma_f32_16x16x32_bf16(af[0], B2[0],  acc2[nt], 0, 0, 0);
        acc1[nt] = __builtin_amdgcn_mfma_f32_16x16x32_bf16(af[1], B1[4],  acc1[nt], 0, 0, 0);
        acc2[nt] = __builtin_amdgcn_mfma_f32_16x16x32_bf16(af[1], B2[4],  acc2[nt], 0, 0, 0);
        acc1[nt] = __builtin_amdgcn_mfma_f32_16x16x32_bf16(af[2], B1[8],  acc1[nt], 0, 0, 0);
        acc2[nt] = __builtin_amdgcn_mfma_f32_16x16x32_bf16(af[2], B2[8],  acc2[nt], 0, 0, 0);
        acc1[nt] = __builtin_amdgcn_mfma_f32_16x16x32_bf16(af[3], B1[12], acc1[nt], 0, 0, 0);
        acc2[nt] = __builtin_amdgcn_mfma_f32_16x16x32_bf16(af[3], B2[12], acc2[nt], 0, 0, 0);
    }

    float bv[8];
    #pragma unroll
    for (int nt = 0; nt < 8; nt++) bv[nt] = bias[nt * 16 + m];

    #pragma unroll
    for (int r = 0; r < 4; r++) {
        int orow = row0 + quad * 4 + r;
        if (orow < N) {
            size_t base = (size_t)orow * 128 + m;
            #pragma unroll
            for (int nt = 0; nt < 8; nt++) {
                support[base + nt * 16] = f2bf(acc1[nt][r]);
                outb[base + nt * 16]    = acc2[nt][r] + bv[nt];
            }
        }
    }
}

// ---------------------------------------------------------------- SpMM + BN stats
// 8-deep gather unroll (two independent acc sets), NSLOT atomic partials
__global__ __launch_bounds__(256) void spmm_stats_k(
    const int* __restrict__ cnt, const unsigned* __restrict__ bucket,
    const int* __restrict__ ovfc, const int2* __restrict__ ovf,
    const unsigned short* __restrict__ sup, float* __restrict__ outb,
    float* __restrict__ partials, int ngroups, int N)
{
    const int r    = threadIdx.x & 31;
    const int slot = threadIdx.x >> 5;
    float s4[4] = {0.f, 0.f, 0.f, 0.f};
    float q4[4] = {0.f, 0.f, 0.f, 0.f};
    __shared__ float red[8][128];

    for (int g = blockIdx.x; g < ngroups; g += gridDim.x) {
        int row = g * 8 + slot;
        if (row >= N) continue;
        int nrec = cnt[row]; if (nrec > CAP) nrec = CAP;
        const unsigned* packed = bucket + (size_t)row * CAP;

        float4 accA = make_float4(0.f, 0.f, 0.f, 0.f);
        float4 accB = make_float4(0.f, 0.f, 0.f, 0.f);
        int e = 0;
        for (; e + 8 <= nrec; e += 8) {
            unsigned pr[8];
            #pragma unroll
            for (int j = 0; j < 8; j++) pr[j] = packed[e + j];
            ushort4 sv[8];
            #pragma unroll
            for (int j = 0; j < 8; j++)
                sv[j] = *(const ushort4*)&sup[((size_t)(pr[j] & 0xFFFFu) << 7) + r * 4];
            #pragma unroll
            for (int j = 0; j < 8; j += 2) {
                float va = rec_val(pr[j]);
                float vb = rec_val(pr[j + 1]);
                accA.x += va * bf2f(sv[j].x);     accA.y += va * bf2f(sv[j].y);
                accA.z += va * bf2f(sv[j].z);     accA.w += va * bf2f(sv[j].w);
                accB.x += vb * bf2f(sv[j + 1].x); accB.y += vb * bf2f(sv[j + 1].y);
                accB.z += vb * bf2f(sv[j + 1].z); accB.w += vb * bf2f(sv[j + 1].w);
            }
        }
        for (; e + 4 <= nrec; e += 4) {
            unsigned p0 = packed[e + 0];
            unsigned p1 = packed[e + 1];
            unsigned p2 = packed[e + 2];
            unsigned p3 = packed[e + 3];
            ushort4 s0 = *(const ushort4*)&sup[((size_t)(p0 & 0xFFFFu) << 7) + r * 4];
            ushort4 s1 = *(const ushort4*)&sup[((size_t)(p1 & 0xFFFFu) << 7) + r * 4];
            ushort4 s2 = *(const ushort4*)&sup[((size_t)(p2 & 0xFFFFu) << 7) + r * 4];
            ushort4 s3 = *(const ushort4*)&sup[((size_t)(p3 & 0xFFFFu) << 7) + r * 4];
            float v0 = rec_val(p0), v1 = rec_val(p1);
            float v2 = rec_val(p2), v3 = rec_val(p3);
            accA.x += v0 * bf2f(s0.x); accA.y += v0 * bf2f(s0.y);
            accA.z += v0 * bf2f(s0.z); accA.w += v0 * bf2f(s0.w);
            accB.x += v1 * bf2f(s1.x); accB.y += v1 * bf2f(s1.y);
            accB.z += v1 * bf2f(s1.z); accB.w += v1 * bf2f(s1.w);
            accA.x += v2 * bf2f(s2.x); accA.y += v2 * bf2f(s2.y);
            accA.z += v2 * bf2f(s2.z); accA.w += v2 * bf2f(s2.w);
            accB.x += v3 * bf2f(s3.x); accB.y += v3 * bf2f(s3.y);
            accB.z += v3 * bf2f(s3.z); accB.w += v3 * bf2f(s3.w);
        }
        for (; e < nrec; e++) {
            unsigned pr = packed[e];
            ushort4 sv = *(const ushort4*)&sup[((size_t)(pr & 0xFFFFu) << 7) + r * 4];
            float v = rec_val(pr);
            accA.x += v * bf2f(sv.x); accA.y += v * bf2f(sv.y);
            accA.z += v * bf2f(sv.z); accA.w += v * bf2f(sv.w);
        }

        int oc = *ovfc;
        if (oc > 0) {                     // rare exactness safety net
            if (oc > OVF_MAX) oc = OVF_MAX;
            for (int i = 0; i < oc; i++) {
                int2 orec = ovf[i];
                if (orec.x == row) {
                    unsigned pr = (unsigned)orec.y;
                    ushort4 sv = *(const ushort4*)&sup[((size_t)(pr & 0xFFFFu) << 7) + r * 4];
                    float v = rec_val(pr);
                    accA.x += v * bf2f(sv.x); accA.y += v * bf2f(sv.y);
                    accA.z += v * bf2f(sv.z); accA.w += v * bf2f(sv.w);
                }
            }
        }

        float4* op = (float4*)&outb[((size_t)row << 7) + r * 4];
        float4 o = *op;
        o.x += accA.x + accB.x; o.y += accA.y + accB.y;
        o.z += accA.z + accB.z; o.w += accA.w + accB.w;
        *op = o;
        s4[0] += o.x; s4[1] += o.y; s4[2] += o.z; s4[3] += o.w;
        q4[0] += o.x * o.x; q4[1] += o.y * o.y; q4[2] += o.z * o.z; q4[3] += o.w * o.w;
    }

    #pragma unroll
    for (int j = 0; j < 4; j++) red[slot][r * 4 + j] = s4[j];
    __syncthreads();
    float ts = 0.f;
    if (threadIdx.x < 128) {
        #pragma unroll
        for (int j = 0; j < 8; j++) ts += red[j][threadIdx.x];
    }
    __syncthreads();
    #pragma unroll
    for (int j = 0; j < 4; j++) red[slot][r * 4 + j] = q4[j];
    __syncthreads();
    if (threadIdx.x < 128) {
        float tq = 0.f;
        #pragma unroll
        for (int j = 0; j < 8; j++) tq += red[j][threadIdx.x];
        float* slotp = partials + (size_t)(blockIdx.x & (NSLOT - 1)) * 256;
        atomicAdd(&slotp[threadIdx.x], ts);        // <=~49 adds/address, spread over 64 slots
        atomicAdd(&slotp[128 + threadIdx.x], tq);
    }
}

// ---------------------------------------------------------------- BN(L1)+residual+score
__global__ __launch_bounds__(256) void score_k(
    const float* __restrict__ outb, const float* __restrict__ partials,
    const float* __restrict__ gamma, const float* __restrict__ beta,
    const float* __restrict__ x, const float* __restrict__ Wc,
    float* __restrict__ s1, float* __restrict__ s2, float invN, int N)
{
    __shared__ float tot[256];
    __shared__ float sa[128], sb[128];
    {
        float a = 0.f;
        #pragma unroll 8
        for (int s = 0; s < NSLOT; s++)
            a += partials[(size_t)s * 256 + threadIdx.x];
        tot[threadIdx.x] = a;
    }
    __syncthreads();
    if (threadIdx.x < 128) {
        int c = threadIdx.x;
        float mean = tot[c] * invN;
        float var  = tot[128 + c] * invN - mean * mean;
        float sc   = gamma[c] * rsqrtf(var + BN_EPS);
        sa[c] = sc;
        sb[c] = beta[c] - mean * sc;
    }
    __syncthreads();

    int total = N * 32;
    int stride = gridDim.x * 256;
    for (int idx = blockIdx.x * 256 + threadIdx.x; idx < total; idx += stride) {
        int c4 = (idx & 31) * 4;
        float4 o = *(const float4*)&outb[(size_t)idx * 4];
        float res[4];
        const float* op = &o.x;
        #pragma unroll
        for (int j = 0; j < 4; j++) {
            float v = op[j] * sa[c4 + j] + sb[c4 + j];
            res[j] = v > 0.f ? v : 0.f;
        }
        float4 xv = *(const float4*)&x[(size_t)idx * 4];
        res[0] += xv.x; res[1] += xv.y; res[2] += xv.z; res[3] += xv.w;
        float4 w1 = *(const float4*)&Wc[c4];
        float4 w2 = *(const float4*)&Wc[128 + c4];
        float a1 = res[0] * w1.x + res[1] * w1.y + res[2] * w1.z + res[3] * w1.w;
        float a2 = res[0] * w2.x + res[1] * w2.y + res[2] * w2.z + res[3] * w2.w;
        #pragma unroll
        for (int off = 1; off < 32; off <<= 1) {
            a1 += __shfl_xor(a1, off);
            a2 += __shfl_xor(a2, off);
        }
        if ((idx & 31) == 0) {
            int row = idx >> 5;
            s1[row] = a1;
            s2[row] = a2;
        }
    }
}

__global__ __launch_bounds__(256) void edge_pred_k(
    const float* __restrict__ s1, const float* __restrict__ s2,
    const int* __restrict__ ei, const float* __restrict__ bc,
    float* __restrict__ outp, int Ep)
{
    int e = blockIdx.x * 256 + threadIdx.x;
    if (e >= Ep) return;
    float v = s1[ei[e]] + s2[ei[Ep + e]] + bc[0];
    outp[e] = 1.f / (1.f + expf(-v));
}

// ================================================================ launch
extern "C" void kernel_launch(void* const* d_in, const int* in_sizes, int n_in,
                              void* d_out, int out_size, void* d_ws, size_t ws_size,
                              hipStream_t stream) {
    const float* x        = (const float*)d_in[0];
    const int*   adj_row  = (const int*)  d_in[1];
    const int*   adj_col  = (const int*)  d_in[2];
    const float* adj_val  = (const float*)d_in[3];
    const int*   ei       = (const int*)  d_in[4];
    const float* W        = (const float*)d_in[5];
    const float* W_self   = (const float*)d_in[6];
    const float* b        = (const float*)d_in[7];
    const float* gamma    = (const float*)d_in[8];
    const float* beta     = (const float*)d_in[9];
    const float* Wc       = (const float*)d_in[10];
    const float* bc       = (const float*)d_in[11];
    float* outp = (float*)d_out;

    int N  = in_sizes[0] / DD;    // 50000
    int E  = in_sizes[1];         // 800000
    int Ep = in_sizes[4] / 2;     // 500000
    float invN = 1.f / (float)N;

    size_t nd = (size_t)N * DD;
    char* p = (char*)d_ws;
    unsigned short* support16 = (unsigned short*)p; p += nd * 2;
    float*          outbA     = (float*)p;          p += nd * 4;
    float*          outbB     = (float*)p;          p += nd * 4;
    unsigned short* Wt4       = (unsigned short*)p; p += 4 * 16384 * 2;
    // zero region: [partialsA | partialsB | cnt | ovfc] contiguous
    float*          partialsA = (float*)p;          p += (size_t)NSLOT * 256 * 4;
    float*          partialsB = (float*)p;          p += (size_t)NSLOT * 256 * 4;
    int*            cnt       = (int*)p;            p += (size_t)N * 4;
    int*            ovfc      = (int*)p;            p += 4;
    unsigned*       bucket    = (unsigned*)p;       p += (size_t)N * CAP * 4;
    int2*           ovf       = (int2*)p;           p += (size_t)OVF_MAX * 8;
    float*          s1        = (float*)p;          p += (size_t)N * 4;
    float*          s2        = (float*)p;

    int gemm_tiles = (N + 63) / 64;
    int ngroups    = (N + 7) / 8;
    int rpp        = (N + 7) / 8;
    int nz         = NSLOT * 256 * 2 + N + 1;

    prep_zero_k<<<32 + (nz + 255) / 256, 256, 0, stream>>>(
        W, W_self, Wt4, (int*)partialsA, nz);

    // layer 0: gemm blocks first, scatter after; total grid <= co-residency
    gemm_l0_scatter<<<gemm_tiles + SCAT_BLOCKS, 256, 0, stream>>>(
        x, Wt4, Wt4 + 16384, b, support16, outbA, N, gemm_tiles,
        adj_row, adj_col, adj_val, cnt, bucket, ovfc, ovf, E, rpp);
    spmm_stats_k<<<SPMM_BLOCKS, 256, 0, stream>>>(
        cnt, bucket, ovfc, ovf, support16, outbA, partialsA, ngroups, N);

    // layer 1 (BN of L0 folded in prologue)
    gemm_bn_k<<<gemm_tiles, 256, 0, stream>>>(
        outbA, Wt4 + 2 * 16384, Wt4 + 3 * 16384, b + DD,
        partialsA, gamma, beta, invN, support16, outbB, N);
    spmm_stats_k<<<SPMM_BLOCKS, 256, 0, stream>>>(
        cnt, bucket, ovfc, ovf, support16, outbB, partialsB, ngroups, N);

    // final BN + residual + factorized predictor
    score_k<<<SPMM_BLOCKS, 256, 0, stream>>>(
        outbB, partialsB, gamma + DD, beta + DD, x, Wc, s1, s2, invN, N);
    edge_pred_k<<<(Ep + 255) / 256, 256, 0, stream>>>(s1, s2, ei, bc, outp, Ep);
}